// Round 4
// baseline (124.383 us; speedup 1.0000x reference)
//
#include <hip/hip_runtime.h>
#include <hip/hip_bf16.h>

// DynamicConv1D fused kernel for MI355X (gfx950) — round 3 (resubmit; round-3
// bench was a GPUAcquisitionTimeout, no results).
//
// Round-2 post-mortem: main kernel 64us (MFMA 39%, LDS ~45%, no pipe
// saturated -> overlap-bound at 2 waves/SIMD; register-pinned at 8 waves/CU).
// ~58us of the 122us total was prep kernels + harness: wprep did 1.6M
// scattered 4B gathers.
// Round-3 changes:
//   1. wprep rewritten: 64 blocks, each reads one 100KB *contiguous* source
//      chunk coalesced into LDS, permutes there, writes Wp coalesced.
//   2. main: per-chunk barrier moved from after-softmax to after-j-loop ->
//      softmax (VALU) of lagging waves overlaps next chunk's MFMAs.

typedef unsigned short u16;
typedef unsigned int u32;
typedef __attribute__((ext_vector_type(8))) short short8;
typedef __attribute__((ext_vector_type(4))) float f32x4;

#define IN_CH 32
#define OUT_CH 32
#define KW 7
#define TSZ 4096
#define BSZ 4
#define CONTR 224          // IN_CH*KW
#define NROWS 7168         // OUT_CH*IN_CH*KW
#define BLK_T 512
#define XS_STRIDE 40       // u16 per xs row (80B: 8B-aligned, bank-spread)
#define XS_ROWS (BLK_T + 6)   // 518
#define SLICE_U16 3584     // one (ch,j) slice: 112 rows * 32 c
#define CH_U16 25088       // one chunk: 7 slices
#define CEXP2 0.54528747f  // log2(e)/sqrt(7)

__device__ __forceinline__ u32 f2bf(float v) {   // f32 -> bf16 bits (RNE)
    u32 b = __float_as_uint(v);
    return (b + 0x7fffu + ((b >> 16) & 1u)) >> 16;
}

__device__ __forceinline__ void glds16(const u16* g, u16* l) {
    // 16B per lane; LDS dest = wave-uniform base (HW adds lane*16)
    __builtin_amdgcn_global_load_lds((__attribute__((address_space(1))) void*)g,
                                     (__attribute__((address_space(3))) void*)l,
                                     16, 0, 0);
}

// ---------------- prep 1: W permute + bf16 + group-swizzle, bias permute ----
// Wp u16 idx = ch*25088 + j*3584 + r'*32 + p'*8 + e,  r' = k*16 + q (tap-major)
// stored group p' holds source group p = p' ^ ((r'>>1)&3)  (c = p*8 + e).
// Source chunk ch is CONTIGUOUS in W: grow = ch*112 + q*7 + k, row len 224.
__global__ __launch_bounds__(512)
void wprep(const float* __restrict__ W, const float* __restrict__ bias,
           u16* __restrict__ Wp, float* __restrict__ bp) {
    __shared__ float ws[CH_U16];        // 100,352 B
    int ch  = blockIdx.x;               // 0..63
    int tid = threadIdx.x;
    const float* src = W + (size_t)ch * CH_U16;
    #pragma unroll
    for (int it = 0; it < 49; ++it)     // coalesced chunk read
        ws[it * 512 + tid] = src[it * 512 + tid];
    __syncthreads();
    u16* dst = Wp + (size_t)ch * CH_U16;
    #pragma unroll
    for (int it = 0; it < 49; ++it) {   // coalesced permuted write
        int oidx = it * 512 + tid;      // = j*3584 + rp*32 + pp*8 + e
        int e  = oidx & 7;
        int pp = (oidx >> 3) & 3;
        int t1 = oidx >> 5;
        int rp = t1 % 112;
        int j  = t1 / 112;
        int p  = pp ^ ((rp >> 1) & 3);
        int c  = p * 8 + e;
        int k  = rp >> 4;
        int q  = rp & 15;
        dst[oidx] = (u16)f2bf(ws[(q * 7 + k) * CONTR + c * 7 + j]);
    }
    if (tid < 112) {
        int k = tid >> 4, q = tid & 15;
        int gp = ch * 16 + q;
        int o = gp >> 5, i = gp & 31;
        bp[ch * 112 + tid] = bias[(o * IN_CH + i) * KW + k];
    }
}

// ---------------- prep 2: x -> xT bf16 [b][t][c] ---------------------------
__global__ __launch_bounds__(256)
void xprep(const float* __restrict__ x, u16* __restrict__ xT) {
    int bid = blockIdx.x;
    int b = bid >> 6;
    int t0 = (bid & 63) * 64;
    __shared__ float lds[32][65];
    int tid = threadIdx.x;
    #pragma unroll
    for (int it = 0; it < 8; ++it) {
        int gi = it * 256 + tid;
        int c = gi >> 6;
        int t = gi & 63;
        lds[c][t] = x[((size_t)b * IN_CH + c) * TSZ + t0 + t];
    }
    __syncthreads();
    #pragma unroll
    for (int it = 0; it < 4; ++it) {
        int wi = it * 256 + tid;
        int t  = wi >> 4;
        int cp = wi & 15;
        u32 b0 = f2bf(lds[cp * 2][t]);
        u32 b1 = f2bf(lds[cp * 2 + 1][t]);
        ((u32*)xT)[((size_t)b * TSZ + t0 + t) * 16 + cp] = b0 | (b1 << 16);
    }
}

// ---------------- main fused kernel ----------------------------------------
__global__ __launch_bounds__(512, 1)
void dconv_main(const u16* __restrict__ Wp, const float* __restrict__ bp,
                const u16* __restrict__ xT, float* __restrict__ out) {
    __shared__ u16 xs[XS_ROWS * XS_STRIDE];   // 41,440 B: x tile [t][c]
    __shared__ u16 wbuf[2][CH_U16];           // 100,352 B: chunk double-buffer

    int tid  = threadIdx.x;
    int lane = tid & 63;
    int wave = tid >> 6;        // 0..7, owns cols wave*64 .. +63
    int g    = lane >> 4;       // 0..3
    int col  = lane & 15;

    int bid = blockIdx.x;
    int b   = bid & 3;
    int tt  = (bid >> 2) & 7;
    int os  = bid >> 5;         // o-split: chunks os*8 .. os*8+7
    int t0  = tt * BLK_T;

    // ---- stage x tile (rows t0-3 .. t0+BLK_T+2, zero-padded) ----
    #pragma unroll
    for (int it = 0; it < 17; ++it) {
        int wi = it * 512 + tid;            // dword (c-pair) index
        if (wi < XS_ROWS * 16) {
            int row = wi >> 4;
            int cp  = wi & 15;
            int t = t0 - 3 + row;
            u32 v = 0;
            if (t >= 0 && t < TSZ)
                v = ((const u32*)xT)[((size_t)b * TSZ + t) * 16 + cp];
            *(u32*)&xs[row * XS_STRIDE + cp * 2] = v;
        }
    }

    // ---- prologue: stage chunk 0 (wave w stages slice j=w) ----
    if (wave < 7) {
        const u16* src = Wp + (size_t)(os * 8) * CH_U16 + wave * SLICE_U16 + lane * 8;
        u16* dst = &wbuf[0][wave * SLICE_U16];
        #pragma unroll
        for (int it = 0; it < 7; ++it) glds16(src + it * 512, dst + it * 512);
    }
    __syncthreads();

    // lane-invariant A-read offset (undoes the Wp group swizzle)
    int laneA = col * 32 + ((g ^ ((col >> 1) & 3)) * 8);
    int colw0 = wave * 64 + col;

    float yacc[4] = {0.f, 0.f, 0.f, 0.f};

    #pragma unroll 1
    for (int ci = 0; ci < 8; ++ci) {
        int cur = ci & 1;
        // stage next chunk into the other buffer (hidden under compute)
        if (ci < 7 && wave < 7) {
            const u16* src = Wp + (size_t)(os * 8 + ci + 1) * CH_U16 + wave * SLICE_U16 + lane * 8;
            u16* dst = &wbuf[cur ^ 1][wave * SLICE_U16];
            #pragma unroll
            for (int it = 0; it < 7; ++it) glds16(src + it * 512, dst + it * 512);
        }

        int ch = os * 8 + ci;
        int cc = ci & 1;

        // bias -> accumulator init (acc reg r maps to row q = g*4+r, m = tap)
        f32x4 acc[7][4];
        const float* bsrc = bp + ch * 112 + g * 4;
        #pragma unroll
        for (int m = 0; m < 7; ++m) {
            f32x4 bv = *(const f32x4*)(bsrc + m * 16);
            acc[m][0] = bv; acc[m][1] = bv; acc[m][2] = bv; acc[m][3] = bv;
        }

        const u16* wl = &wbuf[cur][laneA];
        #pragma unroll
        for (int j = 0; j < 7; ++j) {
            // B fragments for this j (4 col-tiles), from xs
            short8 bf[4];
            #pragma unroll
            for (int ct = 0; ct < 4; ++ct)
                bf[ct] = *(const short8*)&xs[(colw0 + ct * 16 + j) * XS_STRIDE + g * 8];
            #pragma unroll
            for (int m = 0; m < 7; ++m) {
                short8 af = *(const short8*)(wl + j * SLICE_U16 + m * 512);
                acc[m][0] = __builtin_amdgcn_mfma_f32_16x16x32_bf16(af, bf[0], acc[m][0], 0, 0, 0);
                acc[m][1] = __builtin_amdgcn_mfma_f32_16x16x32_bf16(af, bf[1], acc[m][1], 0, 0, 0);
                acc[m][2] = __builtin_amdgcn_mfma_f32_16x16x32_bf16(af, bf[2], acc[m][2], 0, 0, 0);
                acc[m][3] = __builtin_amdgcn_mfma_f32_16x16x32_bf16(af, bf[3], acc[m][3], 0, 0, 0);
            }
        }

        // Barrier HERE (not after softmax): wbuf[cur] reads are done, and the
        // glds16s for chunk ci+1 (issued above, covered by the whole j-loop)
        // drain via the compiler's vmcnt(0)-before-s_barrier. The softmax
        // below touches only registers + xs (never rewritten), so lagging
        // waves' softmax overlaps leading waves' next-chunk MFMAs.
        __syncthreads();

        // ---- softmax over taps (lane-local) + einsum contribution ----
        int ibase = cc * 16 + g * 4;        // i for reg r is ibase + r
        #pragma unroll
        for (int ct = 0; ct < 4; ++ct) {
            int colw = colw0 + ct * 16;
            u32 xv0[7], xv1[7];             // x[b][ibase..+3][t+k-3] (2 dwords)
            #pragma unroll
            for (int k = 0; k < 7; ++k) {
                const u32* px = (const u32*)&xs[(colw + k) * XS_STRIDE + ibase];
                xv0[k] = px[0]; xv1[k] = px[1];
            }
            #pragma unroll
            for (int r = 0; r < 4; ++r) {
                float ssum = 0.f, psum = 0.f;
                #pragma unroll
                for (int k = 0; k < 7; ++k) {
                    // |dw/sqrt7| small -> safe without max subtraction
                    float e = __builtin_amdgcn_exp2f(acc[k][ct][r] * CEXP2);
                    u32 w = (r & 2) ? xv1[k] : xv0[k];
                    float xf = __uint_as_float((r & 1) ? (w & 0xffff0000u) : (w << 16));
                    ssum += e;
                    psum = fmaf(e, xf, psum);
                }
                yacc[ct] += psum * __builtin_amdgcn_rcpf(ssum);
            }
        }

        if (cc == 1) {      // o complete: reduce over lane-groups g, store
            int o = os * 4 + (ci >> 1);
            #pragma unroll
            for (int ct = 0; ct < 4; ++ct) {
                float v = yacc[ct];
                v += __shfl_xor(v, 16, 64);
                v += __shfl_xor(v, 32, 64);
                if (lane < 16)
                    out[((size_t)b * OUT_CH + o) * TSZ + t0 + wave * 64 + ct * 16 + col] = v;
                yacc[ct] = 0.f;
            }
        }
    }
}

// ---------------------------------------------------------------------------
extern "C" void kernel_launch(void* const* d_in, const int* in_sizes, int n_in,
                              void* d_out, int out_size, void* d_ws, size_t ws_size,
                              hipStream_t stream) {
    const float* x    = (const float*)d_in[0];
    const float* W    = (const float*)d_in[1];
    const float* bias = (const float*)d_in[2];
    float* out = (float*)d_out;

    // workspace: Wp bf16 (3,211,264 B) | bp f32 (28,672 B) | xT bf16 (1,048,576 B)
    u16*   Wp = (u16*)d_ws;
    float* bp = (float*)((char*)d_ws + 3211264);
    u16*   xT = (u16*)((char*)d_ws + 3211264 + 28672);

    hipLaunchKernelGGL(wprep, dim3(64), dim3(512), 0, stream, W, bias, Wp, bp);
    hipLaunchKernelGGL(xprep, dim3(BSZ * (TSZ / 64)), dim3(256), 0, stream, x, xT);
    hipLaunchKernelGGL(dconv_main, dim3(256), dim3(512), 0, stream, Wp, bp, xT, out);
}

// Round 6
// 122.349 us; speedup vs baseline: 1.0166x; 1.0166x over previous
//
#include <hip/hip_runtime.h>
#include <hip/hip_bf16.h>

// DynamicConv1D fused kernel for MI355X (gfx950) — round 5 (resubmit; round-5
// bench was a GPUAcquisitionTimeout, no results).
//
// Round-4 post-mortem: (1) total-vs-main gap (~59us) is harness-fixed, only
// dconv_main matters; (2) barrier-after-j-loop alone was neutral -> needs
// setprio arbitration (T5). Main kernel is overlap-bound at 2 waves/SIMD
// (register-pinned): MFMA 61K cy, LDS ~74K+14K-conflict cy, VALU 58K cy in
// a 157K cy runtime.
// Round-5 changes (dconv_main only):
//   1. xs row-bit3 XOR swizzle (16B granularity) at staging-write + B-frag
//      read + softmax read: kills the col/col+8 2-way bank conflict on the
//      softmax b64 reads (3.6M conflict cycles).
//   2. softmax scale log2(e)/sqrt(7) folded into Wp/bp at prep: deletes
//      ~900 v_mul per wave; exp2 applies directly to acc.
//   3. s_setprio(1) around the j-loop MFMA cluster, 0 during softmax phase.

typedef unsigned short u16;
typedef unsigned int u32;
typedef __attribute__((ext_vector_type(8))) short short8;
typedef __attribute__((ext_vector_type(4))) float f32x4;

#define IN_CH 32
#define OUT_CH 32
#define KW 7
#define TSZ 4096
#define BSZ 4
#define CONTR 224          // IN_CH*KW
#define NROWS 7168         // OUT_CH*IN_CH*KW
#define BLK_T 512
#define XS_STRIDE 40       // u16 per xs row (80B)
#define XS_ROWS (BLK_T + 6)   // 518
#define SLICE_U16 3584     // one (ch,j) slice: 112 rows * 32 c
#define CH_U16 25088       // one chunk: 7 slices
#define CEXP2 0.54528747f  // log2(e)/sqrt(7) — folded into Wp/bp at prep

__device__ __forceinline__ u32 f2bf(float v) {   // f32 -> bf16 bits (RNE)
    u32 b = __float_as_uint(v);
    return (b + 0x7fffu + ((b >> 16) & 1u)) >> 16;
}

__device__ __forceinline__ void glds16(const u16* g, u16* l) {
    // 16B per lane; LDS dest = wave-uniform base (HW adds lane*16)
    __builtin_amdgcn_global_load_lds((__attribute__((address_space(1))) void*)g,
                                     (__attribute__((address_space(3))) void*)l,
                                     16, 0, 0);
}

// ---------------- prep 1: W permute + scale + bf16 + group-swizzle ---------
// Wp u16 idx = ch*25088 + j*3584 + r'*32 + p'*8 + e,  r' = k*16 + q (tap-major)
// stored group p' holds source group p = p' ^ ((r'>>1)&3)  (c = p*8 + e).
// Values pre-scaled by CEXP2 so the kernel's exp2 needs no multiply.
__global__ __launch_bounds__(512)
void wprep(const float* __restrict__ W, const float* __restrict__ bias,
           u16* __restrict__ Wp, float* __restrict__ bp) {
    __shared__ float ws[CH_U16];        // 100,352 B
    int ch  = blockIdx.x;               // 0..63
    int tid = threadIdx.x;
    const float* src = W + (size_t)ch * CH_U16;
    #pragma unroll
    for (int it = 0; it < 49; ++it)     // coalesced chunk read
        ws[it * 512 + tid] = src[it * 512 + tid];
    __syncthreads();
    u16* dst = Wp + (size_t)ch * CH_U16;
    #pragma unroll
    for (int it = 0; it < 49; ++it) {   // coalesced permuted write
        int oidx = it * 512 + tid;      // = j*3584 + rp*32 + pp*8 + e
        int e  = oidx & 7;
        int pp = (oidx >> 3) & 3;
        int t1 = oidx >> 5;
        int rp = t1 % 112;
        int j  = t1 / 112;
        int p  = pp ^ ((rp >> 1) & 3);
        int c  = p * 8 + e;
        int k  = rp >> 4;
        int q  = rp & 15;
        dst[oidx] = (u16)f2bf(ws[(q * 7 + k) * CONTR + c * 7 + j] * CEXP2);
    }
    if (tid < 112) {
        int k = tid >> 4, q = tid & 15;
        int gp = ch * 16 + q;
        int o = gp >> 5, i = gp & 31;
        bp[ch * 112 + tid] = bias[(o * IN_CH + i) * KW + k] * CEXP2;
    }
}

// ---------------- prep 2: x -> xT bf16 [b][t][c] ---------------------------
__global__ __launch_bounds__(256)
void xprep(const float* __restrict__ x, u16* __restrict__ xT) {
    int bid = blockIdx.x;
    int b = bid >> 6;
    int t0 = (bid & 63) * 64;
    __shared__ float lds[32][65];
    int tid = threadIdx.x;
    #pragma unroll
    for (int it = 0; it < 8; ++it) {
        int gi = it * 256 + tid;
        int c = gi >> 6;
        int t = gi & 63;
        lds[c][t] = x[((size_t)b * IN_CH + c) * TSZ + t0 + t];
    }
    __syncthreads();
    #pragma unroll
    for (int it = 0; it < 4; ++it) {
        int wi = it * 256 + tid;
        int t  = wi >> 4;
        int cp = wi & 15;
        u32 b0 = f2bf(lds[cp * 2][t]);
        u32 b1 = f2bf(lds[cp * 2 + 1][t]);
        ((u32*)xT)[((size_t)b * TSZ + t0 + t) * 16 + cp] = b0 | (b1 << 16);
    }
}

// ---------------- main fused kernel ----------------------------------------
__global__ __launch_bounds__(512, 1)
void dconv_main(const u16* __restrict__ Wp, const float* __restrict__ bp,
                const u16* __restrict__ xT, float* __restrict__ out) {
    __shared__ u16 xs[XS_ROWS * XS_STRIDE];   // 41,440 B: x tile [t][c], swizzled
    __shared__ u16 wbuf[2][CH_U16];           // 100,352 B: chunk double-buffer

    int tid  = threadIdx.x;
    int lane = tid & 63;
    int wave = tid >> 6;        // 0..7, owns cols wave*64 .. +63
    int g    = lane >> 4;       // 0..3
    int col  = lane & 15;

    int bid = blockIdx.x;
    int b   = bid & 3;
    int tt  = (bid >> 2) & 7;
    int os  = bid >> 5;         // o-split: chunks os*8 .. os*8+7
    int t0  = tt * BLK_T;

    // ---- stage x tile (rows t0-3 .. t0+BLK_T+2, zero-padded) ----
    // Row-bit3 XOR swizzle at 16B granularity: u16-offset-within-row bit 3 is
    // XORed with (row>>3)&1. Kills col/col+8 same-bank collisions on the
    // softmax b64 reads; B-frag b128 bank structure unchanged. Applied
    // identically at write and both read sites.
    #pragma unroll
    for (int it = 0; it < 17; ++it) {
        int wi = it * 512 + tid;            // dword (c-pair) index
        if (wi < XS_ROWS * 16) {
            int row = wi >> 4;
            int cp  = wi & 15;
            int t = t0 - 3 + row;
            u32 v = 0;
            if (t >= 0 && t < TSZ)
                v = ((const u32*)xT)[((size_t)b * TSZ + t) * 16 + cp];
            int sw = ((row >> 3) & 1) << 3;
            *(u32*)&xs[row * XS_STRIDE + ((cp * 2) ^ sw)] = v;
        }
    }

    // ---- prologue: stage chunk 0 (wave w stages slice j=w) ----
    if (wave < 7) {
        const u16* src = Wp + (size_t)(os * 8) * CH_U16 + wave * SLICE_U16 + lane * 8;
        u16* dst = &wbuf[0][wave * SLICE_U16];
        #pragma unroll
        for (int it = 0; it < 7; ++it) glds16(src + it * 512, dst + it * 512);
    }
    __syncthreads();

    // lane-invariant A-read offset (undoes the Wp group swizzle)
    int laneA = col * 32 + ((g ^ ((col >> 1) & 3)) * 8);
    int colw0 = wave * 64 + col;

    float yacc[4] = {0.f, 0.f, 0.f, 0.f};

    #pragma unroll 1
    for (int ci = 0; ci < 8; ++ci) {
        int cur = ci & 1;
        // stage next chunk into the other buffer (hidden under compute)
        if (ci < 7 && wave < 7) {
            const u16* src = Wp + (size_t)(os * 8 + ci + 1) * CH_U16 + wave * SLICE_U16 + lane * 8;
            u16* dst = &wbuf[cur ^ 1][wave * SLICE_U16];
            #pragma unroll
            for (int it = 0; it < 7; ++it) glds16(src + it * 512, dst + it * 512);
        }

        int ch = os * 8 + ci;
        int cc = ci & 1;

        // bias(pre-scaled) -> accumulator init (reg r -> row q = g*4+r, m = tap)
        f32x4 acc[7][4];
        const float* bsrc = bp + ch * 112 + g * 4;
        #pragma unroll
        for (int m = 0; m < 7; ++m) {
            f32x4 bv = *(const f32x4*)(bsrc + m * 16);
            acc[m][0] = bv; acc[m][1] = bv; acc[m][2] = bv; acc[m][3] = bv;
        }

        // ---- MFMA phase at raised priority (T5): waves still in the j-loop
        // outrank waves already in their (VALU) softmax phase.
        __builtin_amdgcn_s_setprio(1);
        const u16* wl = &wbuf[cur][laneA];
        #pragma unroll
        for (int j = 0; j < 7; ++j) {
            short8 bf[4];
            #pragma unroll
            for (int ct = 0; ct < 4; ++ct) {
                int row = colw0 + ct * 16 + j;
                int sw = ((row >> 3) & 1) << 3;
                bf[ct] = *(const short8*)&xs[row * XS_STRIDE + ((g * 8) ^ sw)];
            }
            #pragma unroll
            for (int m = 0; m < 7; ++m) {
                short8 af = *(const short8*)(wl + j * SLICE_U16 + m * 512);
                acc[m][0] = __builtin_amdgcn_mfma_f32_16x16x32_bf16(af, bf[0], acc[m][0], 0, 0, 0);
                acc[m][1] = __builtin_amdgcn_mfma_f32_16x16x32_bf16(af, bf[1], acc[m][1], 0, 0, 0);
                acc[m][2] = __builtin_amdgcn_mfma_f32_16x16x32_bf16(af, bf[2], acc[m][2], 0, 0, 0);
                acc[m][3] = __builtin_amdgcn_mfma_f32_16x16x32_bf16(af, bf[3], acc[m][3], 0, 0, 0);
            }
        }
        __builtin_amdgcn_s_setprio(0);

        // Barrier here: wbuf[cur] reads done; staged chunk ci+1 drains via the
        // compiler's vmcnt(0)-before-s_barrier. Softmax below touches only
        // registers + xs (never rewritten) -> lagging waves' softmax overlaps
        // leading waves' next-chunk MFMAs (which run at prio 1).
        __syncthreads();

        // ---- softmax over taps (lane-local) + einsum contribution ----
        int ibase = cc * 16 + g * 4;        // i for reg r is ibase + r
        #pragma unroll
        for (int ct = 0; ct < 4; ++ct) {
            int colw = colw0 + ct * 16;
            u32 xv0[7], xv1[7];             // x[b][ibase..+3][t+k-3] (2 dwords)
            #pragma unroll
            for (int k = 0; k < 7; ++k) {
                int row = colw + k;
                int sw = ((row >> 3) & 1) << 3;
                const u32* px = (const u32*)&xs[row * XS_STRIDE + (ibase ^ sw)];
                xv0[k] = px[0]; xv1[k] = px[1];
            }
            #pragma unroll
            for (int r = 0; r < 4; ++r) {
                float ssum = 0.f, psum = 0.f;
                #pragma unroll
                for (int k = 0; k < 7; ++k) {
                    // scale pre-folded into Wp/bp; |acc| small -> no max-sub
                    float e = __builtin_amdgcn_exp2f(acc[k][ct][r]);
                    u32 w = (r & 2) ? xv1[k] : xv0[k];
                    float xf = __uint_as_float((r & 1) ? (w & 0xffff0000u) : (w << 16));
                    ssum += e;
                    psum = fmaf(e, xf, psum);
                }
                yacc[ct] += psum * __builtin_amdgcn_rcpf(ssum);
            }
        }

        if (cc == 1) {      // o complete: reduce over lane-groups g, store
            int o = os * 4 + (ci >> 1);
            #pragma unroll
            for (int ct = 0; ct < 4; ++ct) {
                float v = yacc[ct];
                v += __shfl_xor(v, 16, 64);
                v += __shfl_xor(v, 32, 64);
                if (lane < 16)
                    out[((size_t)b * OUT_CH + o) * TSZ + t0 + wave * 64 + ct * 16 + col] = v;
                yacc[ct] = 0.f;
            }
        }
    }
}

// ---------------------------------------------------------------------------
extern "C" void kernel_launch(void* const* d_in, const int* in_sizes, int n_in,
                              void* d_out, int out_size, void* d_ws, size_t ws_size,
                              hipStream_t stream) {
    const float* x    = (const float*)d_in[0];
    const float* W    = (const float*)d_in[1];
    const float* bias = (const float*)d_in[2];
    float* out = (float*)d_out;

    // workspace: Wp bf16 (3,211,264 B) | bp f32 (28,672 B) | xT bf16 (1,048,576 B)
    u16*   Wp = (u16*)d_ws;
    float* bp = (float*)((char*)d_ws + 3211264);
    u16*   xT = (u16*)((char*)d_ws + 3211264 + 28672);

    hipLaunchKernelGGL(wprep, dim3(64), dim3(512), 0, stream, W, bias, Wp, bp);
    hipLaunchKernelGGL(xprep, dim3(BSZ * (TSZ / 64)), dim3(256), 0, stream, x, xT);
    hipLaunchKernelGGL(dconv_main, dim3(256), dim3(512), 0, stream, Wp, bp, xT, out);
}